// Round 9
// baseline (48.556 us; speedup 1.0000x reference)
//
#include <hip/hip_runtime.h>

// Problem constants (B, C, O, K, H, W) = (8, 64, 64, 3, 128, 128)
#define NTAP 9
#define C_DIM 64
#define O_DIM 64
#define HW 128
#define CPAD 72   // LDS w-row stride 144B; with XOR slot swizzle reads are conflict-free

typedef short s16x8 __attribute__((ext_vector_type(8)));
typedef float f32x16 __attribute__((ext_vector_type(16)));

__device__ __forceinline__ unsigned short f2bf(float x) {
    unsigned int u = __float_as_uint(x);
    unsigned int r = (u + 0x7fffu + ((u >> 16) & 1u)) >> 16;
    return (unsigned short)r;
}

// ---------------------------------------------------------------------------
// Pre-kernel: W [C=64][3][3][O=64] f32 -> fragment-major bf16 (d_ws, 72KB).
// Fragment F = ((tap*4 + s)*2 + m)*64 + lane, element e:
//   c = 16*s + 8*(lane>>5) + e,   o = 32*m + (lane&31)
// Same (lane>>5, e) -> k-slot mapping is used for the feat (B) operand, so the
// contraction is correct under any hardware k-slot permutation.
// ---------------------------------------------------------------------------
__global__ void swizzle_W_kernel(const float* __restrict__ W,
                                 unsigned short* __restrict__ Wf) {
    int idx = blockIdx.x * 256 + threadIdx.x;
    if (idx >= NTAP * 4 * 2 * 64 * 8) return;
    int e    = idx & 7;
    int lane = (idx >> 3) & 63;
    int m    = (idx >> 9) & 1;
    int s    = (idx >> 10) & 3;
    int tap  = idx >> 12;
    int c = s * 16 + ((lane >> 5) << 3) + e;
    int o = (m << 5) + (lane & 31);
    Wf[idx] = f2bf(W[c * 576 + tap * 64 + o]);
}

// ---------------------------------------------------------------------------
// Main kernel: one block per (batch, h-PAIR, 64-w half). 256 threads = 4 waves.
// LDS window: 4 rows x 66 w x 64 c bf16 (38KB) -> 4 blocks/CU, 16 waves/CU.
// Wave (m = o-half, pg = w-32-group): TWO 32px x 32o chains (rows h0, h0+1)
// sharing every A-fragment load -> halves Wf L2 traffic.
// LDS slot swizzle: c-octet stored at slot oct ^ ((wi>>3)&3) -> the b128 read
// lane groups {c31, c31+8, +16, +24} land on distinct banks (conflict-free).
// ---------------------------------------------------------------------------
__global__ __launch_bounds__(256, 4) void dyconv_kernel(
    const float* __restrict__ feat, const float* __restrict__ tm,
    const unsigned short* __restrict__ Wf, float* __restrict__ out)
{
    __shared__ __align__(16) unsigned short feat_lds[4][66][CPAD];

    // bijective XCD swizzle: XCD x gets batch x; h-neighbors adjacent in time
    const int flat  = blockIdx.x;             // 0..1023
    const int b     = flat & 7;
    const int inner = flat >> 3;              // 0..127
    const int h0    = (inner >> 1) * 2;       // 0,2,..,126
    const int w0    = (inner & 1) << 6;       // 0 or 64

    const int tid  = threadIdx.x;
    const int lane = tid & 63;
    const int wave = tid >> 6;                // 0..3
    const int m    = wave >> 1;               // o-half
    const int pg   = wave & 1;                // w 32-group
    const int g    = lane >> 5;               // k-slot half
    const int c31  = lane & 31;
    const int pw   = pg * 32 + c31;           // pixel w-offset in tile 0..63
    const int wout = w0 + pw;

    // tm prefetch (independent of LDS; in flight under staging)
    float tmr0[NTAP], tmr1[NTAP];
    #pragma unroll
    for (int t = 0; t < NTAP; ++t) {
        const float* tp = tm + ((size_t)(b * NTAP + t)) * (HW * HW)
                        + (size_t)h0 * HW + wout;
        tmr0[t] = tp[0];
        tmr1[t] = tp[HW];
    }

    // ---- stage 4 input rows (h0-1 .. h0+2), w-span [w0-4, w0+68), 64 c ----
    // unit U = ((r*18)+q)*8 + oct : float4 span of 4w x 8c, packed to bf16.
    // 576 units: each thread does U=tid, tid+256 (batched), tid<64 a 3rd.
    {
        auto unit_addr = [&](int U, int& r, int& q, int& oct, const float*& src,
                             bool& ld) {
            oct = U & 7;
            const int t6 = U >> 3;            // 0..71
            q  = t6 % 18;
            r  = t6 / 18;
            const int hr = h0 - 1 + r;
            const int wb = w0 - 4 + 4 * q;
            ld = (hr >= 0) && (hr < HW) && (wb >= 0) && (wb <= HW - 4);
            src = feat + (((size_t)(b * C_DIM + oct * 8)) * HW + hr) * HW + wb;
        };
        auto unit_store = [&](int r, int q, int oct, const float4* v) {
            #pragma unroll
            for (int i = 0; i < 4; ++i) {
                const int wi = 4 * q - 3 + i;
                if (wi >= 0 && wi <= 65) {
                    const int slot = oct ^ ((wi >> 3) & 3);
                    s16x8 pk;
                    #pragma unroll
                    for (int j = 0; j < 8; ++j) {
                        const float* vf = (const float*)&v[j];
                        pk[j] = (short)f2bf(vf[i]);
                    }
                    *(s16x8*)&feat_lds[r][wi][slot * 8] = pk;
                }
            }
        };

        int r0, q0, o0, r1, q1, o1;
        bool ld0, ld1;
        const float *s0, *s1;
        unit_addr(tid,       r0, q0, o0, s0, ld0);
        unit_addr(tid + 256, r1, q1, o1, s1, ld1);
        float4 v0[8], v1[8];
        #pragma unroll
        for (int j = 0; j < 8; ++j)
            v0[j] = ld0 ? *(const float4*)(s0 + (size_t)j * (HW * HW))
                        : float4{0.f, 0.f, 0.f, 0.f};
        #pragma unroll
        for (int j = 0; j < 8; ++j)
            v1[j] = ld1 ? *(const float4*)(s1 + (size_t)j * (HW * HW))
                        : float4{0.f, 0.f, 0.f, 0.f};
        unit_store(r0, q0, o0, v0);
        unit_store(r1, q1, o1, v1);
        if (tid < 576 - 512) {                // tail: units 512..575
            int r2, q2, o2; bool ld2; const float* s2;
            unit_addr(tid + 512, r2, q2, o2, s2, ld2);
            float4 v2[8];
            #pragma unroll
            for (int j = 0; j < 8; ++j)
                v2[j] = ld2 ? *(const float4*)(s2 + (size_t)j * (HW * HW))
                            : float4{0.f, 0.f, 0.f, 0.f};
            unit_store(r2, q2, o2, v2);
        }
    }

    __syncthreads();

    const s16x8* __restrict__ Wf8 = (const s16x8*)Wf;

    f32x16 acc0 = {0,0,0,0,0,0,0,0,0,0,0,0,0,0,0,0};
    f32x16 acc1 = acc0;

    __builtin_amdgcn_s_setprio(1);
    #pragma unroll
    for (int tap = 0; tap < NTAP; ++tap) {
        const int di = tap / 3;
        const int dj = tap % 3;
        const int wi = pw + dj;               // window index (input w - (w0-1))
        const int cb = (wi >> 3) & 3;         // swizzle key for this column
        f32x16 pa0 = {0,0,0,0,0,0,0,0,0,0,0,0,0,0,0,0};
        f32x16 pa1 = pa0;
        #pragma unroll
        for (int s = 0; s < 4; ++s) {
            const int slot = (2 * s + g) ^ cb;
            s16x8 bf0 = *(const s16x8*)&feat_lds[di    ][wi][slot * 8];
            s16x8 bf1 = *(const s16x8*)&feat_lds[di + 1][wi][slot * 8];
            s16x8 a   = Wf8[((tap * 4 + s) * 2 + m) * 64 + lane];  // shared
            pa0 = __builtin_amdgcn_mfma_f32_32x32x16_bf16(a, bf0, pa0, 0, 0, 0);
            pa1 = __builtin_amdgcn_mfma_f32_32x32x16_bf16(a, bf1, pa1, 0, 0, 0);
        }
        const float tv0 = tmr0[tap];
        const float tv1 = tmr1[tap];
        #pragma unroll
        for (int r = 0; r < 16; ++r) {
            acc0[r] = fmaf(tv0, pa0[r], acc0[r]);
            acc1[r] = fmaf(tv1, pa1[r], acc1[r]);
        }
    }
    __builtin_amdgcn_s_setprio(0);

    // ---- store rows h0, h0+1: D (32x32): col = c31, o = (r&3)+8*(r>>2)+4g+32m
    float* op = out + ((size_t)b * O_DIM) * (HW * HW) + (size_t)h0 * HW + wout;
    #pragma unroll
    for (int r = 0; r < 16; ++r) {
        const int o = (r & 3) + ((r >> 2) << 3) + (g << 2) + (m << 5);
        op[(size_t)o * (HW * HW)]      = acc0[r];
        op[(size_t)o * (HW * HW) + HW] = acc1[r];
    }
}

extern "C" void kernel_launch(void* const* d_in, const int* in_sizes, int n_in,
                              void* d_out, int out_size, void* d_ws, size_t ws_size,
                              hipStream_t stream) {
    const float* feat = (const float*)d_in[0];   // [8,64,128,128] f32
    const float* tm   = (const float*)d_in[1];   // [8,9,16384]    f32
    const float* W    = (const float*)d_in[2];   // [64,3,3,64]    f32
    float* out        = (float*)d_out;           // [8,64,128,128] f32
    unsigned short* Wf = (unsigned short*)d_ws;  // 73728 B scratch

    swizzle_W_kernel<<<dim3(144), dim3(256), 0, stream>>>(W, Wf);
    dyconv_kernel<<<dim3(1024), dim3(256), 0, stream>>>(feat, tm, Wf, out);
}